// Round 7
// baseline (1085.942 us; speedup 1.0000x reference)
//
#include <hip/hip_runtime.h>
#include <stdint.h>

#define B_TOTAL 4096
#define T_STEPS 512
#define IN_DIM 16
#define H1 5
#define H2 50
#define NCLS 20
#define XFS 40           // xf row stride in shorts (80B: 16B-aligned, ~2-way banks)

typedef __attribute__((ext_vector_type(8))) short bf16x8;
typedef __attribute__((ext_vector_type(4))) float f32x4;

#define LOG2E 1.44269504f
#define C2L   2.88539008f   /* 2*log2(e) */
#define C2L2  5.77078016f   /* 4*log2(e) */

// sigma(y_scaled) = rcp1pexp2(-y)            (weights pre-scaled by LOG2E)
// tanh(y_scaled)  = fma(-2, rcp1pexp2(y), 1) (weights pre-scaled by 2*LOG2E)
__device__ inline float rcp1pexp2(float y){
  return __builtin_amdgcn_rcpf(1.0f + __builtin_amdgcn_exp2f(y));
}

// dword = [top16(a) | top16(b)]  (memory shorts: [0]=b, [1]=a)
__device__ inline unsigned pack_top(float a, float b){
  return __builtin_amdgcn_perm(__float_as_uint(a), __float_as_uint(b), 0x07060302u);
}
__device__ inline void cvt_store(unsigned short* dh, unsigned short* dl, float4 v){
  uint2 H, L;
  H.x = pack_top(v.y, v.x);
  H.y = pack_top(v.w, v.z);
  float r0 = v.x - __uint_as_float(__float_as_uint(v.x) & 0xFFFF0000u);
  float r1 = v.y - __uint_as_float(__float_as_uint(v.y) & 0xFFFF0000u);
  float r2 = v.z - __uint_as_float(__float_as_uint(v.z) & 0xFFFF0000u);
  float r3 = v.w - __uint_as_float(__float_as_uint(v.w) & 0xFFFF0000u);
  L.x = pack_top(r1, r0);
  L.y = pack_top(r3, r2);
  *(uint2*)dh = H; *(uint2*)dl = L;
}
__device__ inline void split1(float h, unsigned short& hi, unsigned short& lo){
  unsigned u = __float_as_uint(h);
  hi = (unsigned short)(u >> 16);
  float r = h - __uint_as_float(u & 0xFFFF0000u);
  lo = (unsigned short)(__float_as_uint(r) >> 16);
}
__device__ inline void wsplit(float w, short& hi, short& lo){
  unsigned u = __float_as_uint(w);
  hi = (short)(u >> 16);
  float r = w - __uint_as_float(u & 0xFFFF0000u);
  lo = (short)(__float_as_uint(r) >> 16);
}
// split 8 floats into hi/lo bf16x8 fragments (peel only)
__device__ inline void xsplit(float4 a, float4 b, bf16x8& H, bf16x8& L){
  short h,l;
  wsplit(a.x,h,l); H[0]=h; L[0]=l;
  wsplit(a.y,h,l); H[1]=h; L[1]=l;
  wsplit(a.z,h,l); H[2]=h; L[2]=l;
  wsplit(a.w,h,l); H[3]=h; L[3]=l;
  wsplit(b.x,h,l); H[4]=h; L[4]=l;
  wsplit(b.y,h,l); H[5]=h; L[5]=l;
  wsplit(b.z,h,l); H[6]=h; L[6]=l;
  wsplit(b.w,h,l); H[7]=h; L[7]=l;
}

// raw barrier: no vmcnt drain (x prefetch stays in flight); LDS made visible
// by explicit lgkmcnt(0) before the barrier.
#define LDS_FENCE() __asm__ volatile("s_waitcnt lgkmcnt(0)" ::: "memory")
#define BARRIER()   __asm__ volatile("s_barrier" ::: "memory")

// Fused 2-layer LSTM + FC. grid 128 (32-batch tiles), block 256 (4 waves).
// TWO independent 16-batch groups (A = rows 0-15, B = rows 16-31) per block,
// interleaved in each wave's instruction stream. Rationale (R2/R3 fit):
// step = F(~1700cy, intra-stream phase latency) + per-SIMD issue; a second
// GROUP in the same stream gives the compiler an independent dep-chain to
// fill F's gaps (reads B under MFMA A, act A under MFMA B, writes A under
// act B) — one fence+barrier now covers 2x the work. Weights are shared
// between groups (column property), so the dominant VGPR cost doesn't grow.
// lstm1 folded into wave 3's tiles (cols 48,49 = lstm2; 50..54 = lstm1).
// x pipeline: wave 0 produces both groups' bf16 x fragments one step ahead
// into a 2-slot LDS ring. a2 double-buffered, loop unrolled x2, last pair
// peeled. Bank-XOR swizzle kept from R6 (rsw/wsw identical for both groups
// since ((16+r)>>3)&1 == (r>>3)&1 for r<16).
// Numerics per group identical to the 495us R6.
__global__ __launch_bounds__(256, 1) void lstm_fused_kernel(
    const float* __restrict__ x,
    const float* __restrict__ w_ih1, const float* __restrict__ w_hh1,
    const float* __restrict__ b_ih1, const float* __restrict__ b_hh1,
    const float* __restrict__ w_ih2, const float* __restrict__ w_hh2,
    const float* __restrict__ b_ih2, const float* __restrict__ b_hh2,
    const float* __restrict__ fc_w, const float* __restrict__ fc_b,
    float* __restrict__ out)
{
  const int tid  = threadIdx.x;
  const int lane = tid & 63;
  const int wave = tid >> 6;      // 0..3
  const int l15  = lane & 15;
  const int quad = lane >> 4;
  const int b0   = blockIdx.x * 32;

  // a2[buf][batch32][col72]: h2 0-49 | h1 50-54 | zero 55-63 | pad 64-71
  __shared__ __align__(16) unsigned short a2h[2][32*72], a2l[2][32*72];
  // x fragment ring: [slot2][batch32][k XFS]: k 0-15 = x dims; k>=16 zero
  __shared__ __align__(16) unsigned short xfh[2][32*XFS], xfl[2][32*XFS];
  __shared__ float h2f[32*52];

  const bf16x8 zero8 = {0,0,0,0,0,0,0,0};
  const f32x4  zero4 = {0.f,0.f,0.f,0.f};

  bf16x8 Bh[4][3], Bl[4][3];
  f32x4 biasv[4];
  float cstA[4] = {0.f,0.f,0.f,0.f};  // c-state group A, pre-scaled by 2LOG2E
  float cstB[4] = {0.f,0.f,0.f,0.f};  // c-state group B

  // bank swizzle terms (same for both groups; see header comment)
  const int rsw = ((l15 >> 3) & 1) << 3;   // read-side XOR (shorts)
  const int wsw = (quad >> 1) << 3;        // write-side XOR

#pragma unroll
  for (int tt=0; tt<4; ++tt)
#pragma unroll
    for (int kt=0; kt<3; ++kt){ Bh[tt][kt]=zero8; Bl[tt][kt]=zero8; }

  if (wave < 3){
    const int c = wave*16 + l15;    // lstm2 cell 0..47
#pragma unroll
    for (int tt=0; tt<4; ++tt){
      const float gsc = (tt == 2) ? C2L : LOG2E;
      const int grow = tt*H2 + c;
#pragma unroll
      for (int kt=0; kt<2; ++kt){
#pragma unroll
        for (int j=0;j<8;j++){
          const int kk = kt*32 + quad*8 + j;
          float w = 0.f;
          if (kk < H2)         w = w_hh2[grow*H2 + kk];
          else if (kk < H2+H1) w = w_ih2[grow*H1 + (kk-H2)];
          w *= gsc;
          short hi, lo; wsplit(w, hi, lo);
          Bh[tt][kt][j] = hi; Bl[tt][kt][j] = lo;
        }
      }
      const float bias = gsc * (b_ih2[grow] + b_hh2[grow]);
      biasv[tt][0]=bias; biasv[tt][1]=bias; biasv[tt][2]=bias; biasv[tt][3]=bias;
    }
  } else {
    // wave 3: l15 0,1 -> lstm2 cells 48,49; l15 2..6 -> lstm1 cells 0..4
#pragma unroll
    for (int tt=0; tt<4; ++tt){
      const float gsc = (tt == 2) ? C2L : LOG2E;
      float bias = 0.f;
      if (l15 < 2){
        const int grow = tt*H2 + 48 + l15;
#pragma unroll
        for (int kt=0; kt<2; ++kt){
#pragma unroll
          for (int j=0;j<8;j++){
            const int kk = kt*32 + quad*8 + j;
            float w = 0.f;
            if (kk < H2)         w = w_hh2[grow*H2 + kk];
            else if (kk < H2+H1) w = w_ih2[grow*H1 + (kk-H2)];
            w *= gsc;
            short hi, lo; wsplit(w, hi, lo);
            Bh[tt][kt][j] = hi; Bl[tt][kt][j] = lo;
          }
        }
        bias = gsc * (b_ih2[grow] + b_hh2[grow]);
      } else if (l15 < 7){
        const int e = l15 - 2;
        const int grow = tt*H1 + e;
#pragma unroll
        for (int j=0;j<8;j++){
          const int kk = 32 + quad*8 + j;   // chunk1 global k (h1 at 50..54)
          float w1 = (kk >= H2 && kk < H2+H1) ? gsc * w_hh1[grow*H1 + (kk-H2)] : 0.f;
          short hi, lo; wsplit(w1, hi, lo);
          Bh[tt][1][j] = hi; Bl[tt][1][j] = lo;
          const int k2 = quad*8 + j;        // chunk2 k (x dims)
          float w2 = (k2 < IN_DIM) ? gsc * w_ih1[grow*IN_DIM + k2] : 0.f;
          wsplit(w2, hi, lo);
          Bh[tt][2][j] = hi; Bl[tt][2][j] = lo;
        }
        bias = gsc * (b_ih1[grow] + b_hh1[grow]);
      }
      biasv[tt][0]=bias; biasv[tt][1]=bias; biasv[tt][2]=bias; biasv[tt][3]=bias;
    }
  }

  // ---- zero LDS state ----
  { unsigned short* p = &a2h[0][0]; for (int i=tid;i<2*32*72;i+=256)  p[i]=0; }
  { unsigned short* p = &a2l[0][0]; for (int i=tid;i<2*32*72;i+=256)  p[i]=0; }
  { unsigned short* p = &xfh[0][0]; for (int i=tid;i<2*32*XFS;i+=256) p[i]=0; }
  { unsigned short* p = &xfl[0][0]; for (int i=tid;i<2*32*XFS;i+=256) p[i]=0; }
  __syncthreads();   // zeros visible before any data writes

  // ---- x producer (wave 0, 64 lanes): batches pxb (A) and 16+pxb (B) ----
  const bool xprod = (wave == 0);
  const int pxb = lane >> 2;
  const int pxd = (lane & 3) * 4;
  const float* pxbaseA = &x[(size_t)(b0+pxb   )*T_STEPS*IN_DIM + pxd];
  const float* pxbaseB = &x[(size_t)(b0+16+pxb)*T_STEPS*IN_DIM + pxd];
  float4 PA_A, PA_B, PB_A, PB_B;
  if (xprod){
    float4 v1a = *(const float4*)(pxbaseA + 1*IN_DIM);   // x(1) -> slot 1
    float4 v1b = *(const float4*)(pxbaseB + 1*IN_DIM);
    cvt_store(&xfh[1][pxb*XFS+pxd],      &xfl[1][pxb*XFS+pxd],      v1a);
    cvt_store(&xfh[1][(16+pxb)*XFS+pxd], &xfl[1][(16+pxb)*XFS+pxd], v1b);
    PA_A = *(const float4*)(pxbaseA + 2*IN_DIM);         // x(2), written at T=0
    PA_B = *(const float4*)(pxbaseB + 2*IN_DIM);
  }

  // ---- peel: wave 3 computes h1(0) from x(0) into a2[0], both groups ----
  if (wave == 3){
#pragma unroll
    for (int g=0; g<2; ++g){
      bf16x8 XAh = zero8, XAl = zero8;
      if (quad < 2){
        const float* xp = &x[(size_t)(b0+g*16+l15)*T_STEPS*IN_DIM + quad*8];
        xsplit(*(const float4*)xp, *(const float4*)(xp+4), XAh, XAl);
      }
      f32x4 acc[4];
#pragma unroll
      for (int tt=0; tt<4; ++tt){
        f32x4 c2 = __builtin_amdgcn_mfma_f32_16x16x32_bf16(XAh, Bh[tt][2], biasv[tt], 0,0,0);
        c2 = __builtin_amdgcn_mfma_f32_16x16x32_bf16(XAl, Bh[tt][2], c2, 0,0,0);
        c2 = __builtin_amdgcn_mfma_f32_16x16x32_bf16(XAh, Bl[tt][2], c2, 0,0,0);
        acc[tt] = c2;
      }
      const bool isl1 = (l15 >= 2) && (l15 < 7);
#pragma unroll
      for (int r=0;r<4;r++){
        float gi = rcp1pexp2(-acc[0][r]);
        float gf = rcp1pexp2(-acc[1][r]);
        float gg = fmaf(-C2L2, rcp1pexp2(acc[2][r]), C2L);
        float go = rcp1pexp2(-acc[3][r]);
        float cn0 = (g==0) ? cstA[r] : cstB[r];
        float cn = fmaf(gf, cn0, gi * gg);
        if (isl1){
          if (g==0) cstA[r] = cn; else cstB[r] = cn;
          float h = go * fmaf(-2.0f, rcp1pexp2(cn), 1.0f);
          unsigned short hh, hl; split1(h, hh, hl);
          const int row = g*16 + quad*4 + r;
          a2h[0][row*72 + ((48 + l15) ^ wsw)] = hh;
          a2l[0][row*72 + ((48 + l15) ^ wsw)] = hl;
        }
      }
    }
  }
  LDS_FENCE(); BARRIER();

// per-group activation + h-write (GO_ = 0 or 16, CST_ = cstA/cstB)
#define ACT_STORE(ACC_, CST_, GO_, WR_, LAST_) do { \
    if (wave < 3){ \
      const int wrb = ((GO_) + quad*4)*72 + ((wave*16 + l15) ^ wsw); \
      _Pragma("unroll") \
      for (int r=0;r<4;r++){ \
        float gi = rcp1pexp2(-ACC_[0][r]); \
        float gf = rcp1pexp2(-ACC_[1][r]); \
        float gg = fmaf(-C2L2, rcp1pexp2(ACC_[2][r]), C2L); \
        float go = rcp1pexp2(-ACC_[3][r]); \
        CST_[r] = fmaf(gf, CST_[r], gi * gg); \
        float h = go * fmaf(-2.0f, rcp1pexp2(CST_[r]), 1.0f); \
        unsigned short hh, hl; split1(h, hh, hl); \
        a2h[WR_][wrb + r*72] = hh; \
        a2l[WR_][wrb + r*72] = hl; \
        if (LAST_){ \
          out[(size_t)B_TOTAL*NCLS + (size_t)(b0+(GO_)+quad*4+r)*H2 + wave*16+l15] = h; \
          h2f[((GO_)+quad*4+r)*52 + wave*16+l15] = h; \
        } \
      } \
    } else { \
      const int wrb = ((GO_) + quad*4)*72 + ((48 + l15) ^ wsw); \
      const bool wv_ = l15 < 7; \
      _Pragma("unroll") \
      for (int r=0;r<4;r++){ \
        float gi = rcp1pexp2(-ACC_[0][r]); \
        float gf = rcp1pexp2(-ACC_[1][r]); \
        float gg = fmaf(-C2L2, rcp1pexp2(ACC_[2][r]), C2L); \
        float go = rcp1pexp2(-ACC_[3][r]); \
        CST_[r] = fmaf(gf, CST_[r], gi * gg); \
        float h = go * fmaf(-2.0f, rcp1pexp2(CST_[r]), 1.0f); \
        if (wv_){ \
          unsigned short hh, hl; split1(h, hh, hl); \
          a2h[WR_][wrb + r*72] = hh; \
          a2l[WR_][wrb + r*72] = hl; \
          if ((LAST_) && l15 < 2){ \
            out[(size_t)B_TOTAL*NCLS + (size_t)(b0+(GO_)+quad*4+r)*H2 + 48+l15] = h; \
            h2f[((GO_)+quad*4+r)*52 + 48+l15] = h; \
          } \
        } \
      } \
    } \
  } while(0)

// 12 (waves 0-2) or 18 (wave 3) MFMAs for one group; RB_ = a2 row base (shorts)
#define GROUP_MFMA(ACC_, RB_, XH_, XL_) do { \
    bf16x8 ah0 = *(const bf16x8*)&a2h[RD__][(RB_) +      ((quad*8) ^ rsw)]; \
    bf16x8 al0 = *(const bf16x8*)&a2l[RD__][(RB_) +      ((quad*8) ^ rsw)]; \
    bf16x8 ah1 = *(const bf16x8*)&a2h[RD__][(RB_) + 32 + ((quad*8) ^ rsw)]; \
    bf16x8 al1 = *(const bf16x8*)&a2l[RD__][(RB_) + 32 + ((quad*8) ^ rsw)]; \
    if (wave < 3){ \
      _Pragma("unroll") \
      for (int tt=0; tt<4; ++tt){ \
        f32x4 c0 = __builtin_amdgcn_mfma_f32_16x16x32_bf16(ah0, Bh[tt][0], biasv[tt], 0,0,0); \
        c0 = __builtin_amdgcn_mfma_f32_16x16x32_bf16(al0, Bh[tt][0], c0, 0,0,0); \
        c0 = __builtin_amdgcn_mfma_f32_16x16x32_bf16(ah0, Bl[tt][0], c0, 0,0,0); \
        f32x4 c1 = __builtin_amdgcn_mfma_f32_16x16x32_bf16(ah1, Bh[tt][1], zero4, 0,0,0); \
        c1 = __builtin_amdgcn_mfma_f32_16x16x32_bf16(al1, Bh[tt][1], c1, 0,0,0); \
        c1 = __builtin_amdgcn_mfma_f32_16x16x32_bf16(ah1, Bl[tt][1], c1, 0,0,0); \
        ACC_[tt] = c0 + c1; \
      } \
    } else { \
      _Pragma("unroll") \
      for (int tt=0; tt<4; ++tt){ \
        f32x4 c0 = __builtin_amdgcn_mfma_f32_16x16x32_bf16(ah0, Bh[tt][0], biasv[tt], 0,0,0); \
        c0 = __builtin_amdgcn_mfma_f32_16x16x32_bf16(al0, Bh[tt][0], c0, 0,0,0); \
        c0 = __builtin_amdgcn_mfma_f32_16x16x32_bf16(ah0, Bl[tt][0], c0, 0,0,0); \
        f32x4 c1 = __builtin_amdgcn_mfma_f32_16x16x32_bf16(ah1, Bh[tt][1], zero4, 0,0,0); \
        c1 = __builtin_amdgcn_mfma_f32_16x16x32_bf16(al1, Bh[tt][1], c1, 0,0,0); \
        c1 = __builtin_amdgcn_mfma_f32_16x16x32_bf16(ah1, Bl[tt][1], c1, 0,0,0); \
        f32x4 c2 = __builtin_amdgcn_mfma_f32_16x16x32_bf16(XH_, Bh[tt][2], zero4, 0,0,0); \
        c2 = __builtin_amdgcn_mfma_f32_16x16x32_bf16(XL_, Bh[tt][2], c2, 0,0,0); \
        c2 = __builtin_amdgcn_mfma_f32_16x16x32_bf16(XH_, Bl[tt][2], c2, 0,0,0); \
        ACC_[tt] = (c0 + c1) + c2; \
      } \
    } \
  } while(0)

#define MAIN_BODY(T_, RD_, WR_, PWA_, PWB_, PLA_, PLB_, LAST_) do { \
    const int RD__ = (RD_); \
    if (xprod){ \
      cvt_store(&xfh[RD_][pxb*XFS+pxd],      &xfl[RD_][pxb*XFS+pxd],      PWA_); \
      cvt_store(&xfh[RD_][(16+pxb)*XFS+pxd], &xfl[RD_][(16+pxb)*XFS+pxd], PWB_); \
      const int nidx_ = ((T_)+3 < T_STEPS) ? (T_)+3 : T_STEPS-1; \
      PLA_ = *(const float4*)(pxbaseA + (size_t)nidx_*IN_DIM); \
      PLB_ = *(const float4*)(pxbaseB + (size_t)nidx_*IN_DIM); \
    } \
    bf16x8 xfHA = zero8, xfLA = zero8, xfHB = zero8, xfLB = zero8; \
    if (wave == 3){ \
      xfHA = *(const bf16x8*)&xfh[WR_][l15*XFS + quad*8]; \
      xfLA = *(const bf16x8*)&xfl[WR_][l15*XFS + quad*8]; \
      xfHB = *(const bf16x8*)&xfh[WR_][(16+l15)*XFS + quad*8]; \
      xfLB = *(const bf16x8*)&xfl[WR_][(16+l15)*XFS + quad*8]; \
    } \
    f32x4 accA[4], accB[4]; \
    GROUP_MFMA(accA, l15*72,        xfHA, xfLA); \
    GROUP_MFMA(accB, (16+l15)*72,   xfHB, xfLB); \
    ACT_STORE(accA, cstA, 0,  WR_, LAST_); \
    ACT_STORE(accB, cstB, 16, WR_, LAST_); \
  } while(0)

  // main loop, unrolled x2: compile-time buffer parity and x ping-pong.
  // step T: reads a2[T&1] + xf[(T+1)&1]; writes a2[(T+1)&1]; producer writes
  // xf[T&1] (x(T+2)) and loads x(T+3). Last pair (510,511) peeled.
  for (int t2 = 0; t2 < T_STEPS-2; t2 += 2){
    MAIN_BODY(t2,   0, 1, PA_A, PA_B, PB_A, PB_B, 0);
    LDS_FENCE(); BARRIER();
    MAIN_BODY(t2+1, 1, 0, PB_A, PB_B, PA_A, PA_B, 0);
    LDS_FENCE(); BARRIER();
  }
  MAIN_BODY(T_STEPS-2, 0, 1, PA_A, PA_B, PB_A, PB_B, 0);
  LDS_FENCE(); BARRIER();
  MAIN_BODY(T_STEPS-1, 1, 0, PB_A, PB_B, PA_A, PA_B, 1);

#undef MAIN_BODY
#undef GROUP_MFMA
#undef ACT_STORE

  __syncthreads();
  // fused FC: 32 batches x 20 outputs = 640 results on 256 threads
  for (int i = tid; i < 32*NCLS; i += 256){
    const int b = i / NCLS, o = i % NCLS;
    float s = fc_b[o];
#pragma unroll 10
    for (int k=0;k<H2;k++) s += fc_w[o*H2+k] * h2f[b*52+k];
    out[(size_t)(b0+b)*NCLS + o] = s;
  }
}

extern "C" void kernel_launch(void* const* d_in, const int* in_sizes, int n_in,
                              void* d_out, int out_size, void* d_ws, size_t ws_size,
                              hipStream_t stream) {
  const float* x     = (const float*)d_in[0];
  const float* w_ih1 = (const float*)d_in[1];
  const float* w_hh1 = (const float*)d_in[2];
  const float* b_ih1 = (const float*)d_in[3];
  const float* b_hh1 = (const float*)d_in[4];
  const float* w_ih2 = (const float*)d_in[5];
  const float* w_hh2 = (const float*)d_in[6];
  const float* b_ih2 = (const float*)d_in[7];
  const float* b_hh2 = (const float*)d_in[8];
  const float* fc_w  = (const float*)d_in[9];
  const float* fc_b  = (const float*)d_in[10];
  float* out = (float*)d_out;

  lstm_fused_kernel<<<dim3(B_TOTAL/32), dim3(256), 0, stream>>>(
      x, w_ih1, w_hh1, b_ih1, b_hh1, w_ih2, w_hh2, b_ih2, b_hh2, fc_w, fc_b, out);
}

// Round 8
// 589.819 us; speedup vs baseline: 1.8411x; 1.8411x over previous
//
#include <hip/hip_runtime.h>
#include <stdint.h>

#define B_TOTAL 4096
#define T_STEPS 512
#define IN_DIM 16
#define H1 5
#define H2 50
#define NCLS 20
#define XFS 40           // xf row stride in shorts (80B: 16B-aligned, ~2-way banks)

typedef __attribute__((ext_vector_type(8))) short bf16x8;
typedef __attribute__((ext_vector_type(4))) float f32x4;

#define LOG2E 1.44269504f
#define C2L   2.88539008f   /* 2*log2(e) */

// Fused cell update, 8 transcendentals (5 exp2 + 3 rcp; was 5+5):
//   sigma(i)*tanhs(g) = C2L*(Eg-1)*rcp((1+Ei)(1+Eg))
//   sigma(o)*tanhs(c) = (Ec-1)*rcp((1+Eo)(1+Ec))
// (weights pre-scaled: i,f,o by LOG2E; g by 2LOG2E; cst pre-scaled by 2LOG2E)
#define CELL_UPDATE(A0_,A1_,A2_,A3_,CST_,H_) do { \
    float Ei_ = __builtin_amdgcn_exp2f(-(A0_)); \
    float Ef_ = __builtin_amdgcn_exp2f(-(A1_)); \
    float Eg_ = __builtin_amdgcn_exp2f( (A2_)); \
    float Eo_ = __builtin_amdgcn_exp2f(-(A3_)); \
    float gf_ = __builtin_amdgcn_rcpf(1.0f + Ef_); \
    float R1_ = __builtin_amdgcn_rcpf((1.0f + Ei_) * (1.0f + Eg_)); \
    float s1_ = fmaf(C2L, Eg_, -C2L); \
    CST_ = fmaf(gf_, CST_, s1_ * R1_); \
    float Ec_ = __builtin_amdgcn_exp2f(CST_); \
    float R2_ = __builtin_amdgcn_rcpf((1.0f + Eo_) * (1.0f + Ec_)); \
    H_ = (Ec_ - 1.0f) * R2_; \
  } while(0)

// dword = [top16(a) | top16(b)]  (memory shorts: [0]=b, [1]=a)
__device__ inline unsigned pack_top(float a, float b){
  return __builtin_amdgcn_perm(__float_as_uint(a), __float_as_uint(b), 0x07060302u);
}
__device__ inline void cvt_store(unsigned short* dh, unsigned short* dl, float4 v){
  uint2 H, L;
  H.x = pack_top(v.y, v.x);
  H.y = pack_top(v.w, v.z);
  float r0 = v.x - __uint_as_float(__float_as_uint(v.x) & 0xFFFF0000u);
  float r1 = v.y - __uint_as_float(__float_as_uint(v.y) & 0xFFFF0000u);
  float r2 = v.z - __uint_as_float(__float_as_uint(v.z) & 0xFFFF0000u);
  float r3 = v.w - __uint_as_float(__float_as_uint(v.w) & 0xFFFF0000u);
  L.x = pack_top(r1, r0);
  L.y = pack_top(r3, r2);
  *(uint2*)dh = H; *(uint2*)dl = L;
}
__device__ inline void split1(float h, unsigned short& hi, unsigned short& lo){
  unsigned u = __float_as_uint(h);
  hi = (unsigned short)(u >> 16);
  float r = h - __uint_as_float(u & 0xFFFF0000u);
  lo = (unsigned short)(__float_as_uint(r) >> 16);
}
__device__ inline void wsplit(float w, short& hi, short& lo){
  unsigned u = __float_as_uint(w);
  hi = (short)(u >> 16);
  float r = w - __uint_as_float(u & 0xFFFF0000u);
  lo = (short)(__float_as_uint(r) >> 16);
}
// split 8 floats into hi/lo bf16x8 fragments (peel only)
__device__ inline void xsplit(float4 a, float4 b, bf16x8& H, bf16x8& L){
  short h,l;
  wsplit(a.x,h,l); H[0]=h; L[0]=l;
  wsplit(a.y,h,l); H[1]=h; L[1]=l;
  wsplit(a.z,h,l); H[2]=h; L[2]=l;
  wsplit(a.w,h,l); H[3]=h; L[3]=l;
  wsplit(b.x,h,l); H[4]=h; L[4]=l;
  wsplit(b.y,h,l); H[5]=h; L[5]=l;
  wsplit(b.z,h,l); H[6]=h; L[6]=l;
  wsplit(b.w,h,l); H[7]=h; L[7]=l;
}

// raw barrier: no vmcnt drain (x prefetch stays in flight); LDS made visible
// by explicit lgkmcnt(0) before the barrier.
#define LDS_FENCE() __asm__ volatile("s_waitcnt lgkmcnt(0)" ::: "memory")
#define BARRIER()   __asm__ volatile("s_barrier" ::: "memory")

// Fused 2-layer LSTM + FC. grid 256 (16-batch tiles, 1 block/CU), block 256
// (4 waves, 1/SIMD). lstm1 folded into wave 3's MFMA tiles (cols 48,49 =
// lstm2 cells; 50..54 = lstm1 cells, l15 2..6).
// Model (R3/R7 A/B): step ~= max-wave instruction stream (issue+latency) +
// ~60ns barrier floor; neither co-resident waves (R3) nor in-stream second
// dep-chains (R7) fill it. Only shrinking the stream pays. This rev cuts the
// act block from 10 to 8 quarter-rate transcendentals per cell via rcp-fusion
// (CELL_UPDATE above) — mathematically identical, ~-48cy/step/wave.
// x pipeline: wave 0 produces bf16 x fragments one step ahead into a 2-slot
// LDS ring; wave 3 consumes them as its chunk2 A-operand. a2 double-buffered,
// loop unrolled x2, last pair peeled, R6 bank-XOR swizzle kept.
__global__ __launch_bounds__(256, 1) void lstm_fused_kernel(
    const float* __restrict__ x,
    const float* __restrict__ w_ih1, const float* __restrict__ w_hh1,
    const float* __restrict__ b_ih1, const float* __restrict__ b_hh1,
    const float* __restrict__ w_ih2, const float* __restrict__ w_hh2,
    const float* __restrict__ b_ih2, const float* __restrict__ b_hh2,
    const float* __restrict__ fc_w, const float* __restrict__ fc_b,
    float* __restrict__ out)
{
  const int tid  = threadIdx.x;
  const int lane = tid & 63;
  const int wave = tid >> 6;      // 0..3
  const int l15  = lane & 15;
  const int quad = lane >> 4;
  const int b0   = blockIdx.x * 16;

  // a2[buf][batch16][col72]: h2 0-49 | h1 50-54 | zero 55-63 | pad 64-71
  __shared__ __align__(16) unsigned short a2h[2][16*72], a2l[2][16*72];
  // x fragment ring: [slot2][batch16][k XFS]: k 0-15 = x dims; k>=16 zero
  __shared__ __align__(16) unsigned short xfh[2][16*XFS], xfl[2][16*XFS];
  __shared__ float h2f[16*52];

  const bf16x8 zero8 = {0,0,0,0,0,0,0,0};
  const f32x4  zero4 = {0.f,0.f,0.f,0.f};

  bf16x8 Bh[4][3], Bl[4][3];
  f32x4 biasv[4];
  float cst[4] = {0.f,0.f,0.f,0.f};   // c-state, pre-scaled by 2LOG2E

  // bank swizzle terms: reads keyed by batch=l15, writes keyed by row=quad*4+r
  const int rsw = ((l15 >> 3) & 1) << 3;   // read-side XOR (shorts)
  const int wsw = (quad >> 1) << 3;        // write-side XOR

#pragma unroll
  for (int tt=0; tt<4; ++tt)
#pragma unroll
    for (int kt=0; kt<3; ++kt){ Bh[tt][kt]=zero8; Bl[tt][kt]=zero8; }

  if (wave < 3){
    const int c = wave*16 + l15;    // lstm2 cell 0..47
#pragma unroll
    for (int tt=0; tt<4; ++tt){
      const float gsc = (tt == 2) ? C2L : LOG2E;
      const int grow = tt*H2 + c;
#pragma unroll
      for (int kt=0; kt<2; ++kt){
#pragma unroll
        for (int j=0;j<8;j++){
          const int kk = kt*32 + quad*8 + j;
          float w = 0.f;
          if (kk < H2)         w = w_hh2[grow*H2 + kk];
          else if (kk < H2+H1) w = w_ih2[grow*H1 + (kk-H2)];
          w *= gsc;
          short hi, lo; wsplit(w, hi, lo);
          Bh[tt][kt][j] = hi; Bl[tt][kt][j] = lo;
        }
      }
      const float bias = gsc * (b_ih2[grow] + b_hh2[grow]);
      biasv[tt][0]=bias; biasv[tt][1]=bias; biasv[tt][2]=bias; biasv[tt][3]=bias;
    }
  } else {
    // wave 3: l15 0,1 -> lstm2 cells 48,49; l15 2..6 -> lstm1 cells 0..4
#pragma unroll
    for (int tt=0; tt<4; ++tt){
      const float gsc = (tt == 2) ? C2L : LOG2E;
      float bias = 0.f;
      if (l15 < 2){
        const int grow = tt*H2 + 48 + l15;
#pragma unroll
        for (int kt=0; kt<2; ++kt){
#pragma unroll
          for (int j=0;j<8;j++){
            const int kk = kt*32 + quad*8 + j;
            float w = 0.f;
            if (kk < H2)         w = w_hh2[grow*H2 + kk];
            else if (kk < H2+H1) w = w_ih2[grow*H1 + (kk-H2)];
            w *= gsc;
            short hi, lo; wsplit(w, hi, lo);
            Bh[tt][kt][j] = hi; Bl[tt][kt][j] = lo;
          }
        }
        bias = gsc * (b_ih2[grow] + b_hh2[grow]);
      } else if (l15 < 7){
        const int e = l15 - 2;
        const int grow = tt*H1 + e;
#pragma unroll
        for (int j=0;j<8;j++){
          const int kk = 32 + quad*8 + j;   // chunk1 global k (h1 at 50..54)
          float w1 = (kk >= H2 && kk < H2+H1) ? gsc * w_hh1[grow*H1 + (kk-H2)] : 0.f;
          short hi, lo; wsplit(w1, hi, lo);
          Bh[tt][1][j] = hi; Bl[tt][1][j] = lo;
          const int k2 = quad*8 + j;        // chunk2 k (x dims)
          float w2 = (k2 < IN_DIM) ? gsc * w_ih1[grow*IN_DIM + k2] : 0.f;
          wsplit(w2, hi, lo);
          Bh[tt][2][j] = hi; Bl[tt][2][j] = lo;
        }
        bias = gsc * (b_ih1[grow] + b_hh1[grow]);
      }
      biasv[tt][0]=bias; biasv[tt][1]=bias; biasv[tt][2]=bias; biasv[tt][3]=bias;
    }
  }

  // ---- zero LDS state ----
  { unsigned short* p = &a2h[0][0]; for (int i=tid;i<2*16*72;i+=256)  p[i]=0; }
  { unsigned short* p = &a2l[0][0]; for (int i=tid;i<2*16*72;i+=256)  p[i]=0; }
  { unsigned short* p = &xfh[0][0]; for (int i=tid;i<2*16*XFS;i+=256) p[i]=0; }
  { unsigned short* p = &xfl[0][0]; for (int i=tid;i<2*16*XFS;i+=256) p[i]=0; }
  __syncthreads();   // zeros visible before any data writes

  // ---- x producer (wave 0, 64 lanes): batch pxb, dims pxd..pxd+3 ----
  const bool xprod = (wave == 0);
  const int pxb = lane >> 2;
  const int pxd = (lane & 3) * 4;
  const float* pxbase = &x[(size_t)(b0+pxb)*T_STEPS*IN_DIM + pxd];
  float4 PA, PB;
  if (xprod){
    float4 v1 = *(const float4*)(pxbase + 1*IN_DIM);     // x(1) -> slot 1
    cvt_store(&xfh[1][pxb*XFS+pxd], &xfl[1][pxb*XFS+pxd], v1);
    PA = *(const float4*)(pxbase + 2*IN_DIM);            // x(2), written at T=0
  }

  // ---- peel: wave 3 computes h1(0) from x(0) into a2[0] ----
  if (wave == 3){
    bf16x8 XAh = zero8, XAl = zero8;
    if (quad < 2){
      const float* xp = &x[(size_t)(b0+l15)*T_STEPS*IN_DIM + quad*8];
      xsplit(*(const float4*)xp, *(const float4*)(xp+4), XAh, XAl);
    }
    f32x4 acc[4];
#pragma unroll
    for (int tt=0; tt<4; ++tt){
      f32x4 c2 = __builtin_amdgcn_mfma_f32_16x16x32_bf16(XAh, Bh[tt][2], biasv[tt], 0,0,0);
      c2 = __builtin_amdgcn_mfma_f32_16x16x32_bf16(XAl, Bh[tt][2], c2, 0,0,0);
      c2 = __builtin_amdgcn_mfma_f32_16x16x32_bf16(XAh, Bl[tt][2], c2, 0,0,0);
      acc[tt] = c2;
    }
    const bool isl1 = (l15 >= 2) && (l15 < 7);
#pragma unroll
    for (int r=0;r<4;r++){
      float cpre = cst[r], h;
      CELL_UPDATE(acc[0][r], acc[1][r], acc[2][r], acc[3][r], cpre, h);
      if (isl1){
        cst[r] = cpre;
        unsigned short hh, hl; split1(h, hh, hl);
        const int row = quad*4 + r;
        a2h[0][row*72 + ((48 + l15) ^ wsw)] = hh;
        a2l[0][row*72 + ((48 + l15) ^ wsw)] = hl;
      }
    }
  }
  LDS_FENCE(); BARRIER();

#define MAIN_BODY(T_, RD_, WR_, PXW_, PXL_, LAST_) do { \
    if (xprod){ \
      cvt_store(&xfh[RD_][pxb*XFS+pxd], &xfl[RD_][pxb*XFS+pxd], PXW_); /* x(T+2) */ \
      const int nidx_ = ((T_)+3 < T_STEPS) ? (T_)+3 : T_STEPS-1; \
      PXL_ = *(const float4*)(pxbase + (size_t)nidx_*IN_DIM);          /* x(T+3) */ \
    } \
    const int rb_ = l15*72; \
    bf16x8 ah0 = *(const bf16x8*)&a2h[RD_][rb_ +      ((quad*8) ^ rsw)]; \
    bf16x8 al0 = *(const bf16x8*)&a2l[RD_][rb_ +      ((quad*8) ^ rsw)]; \
    bf16x8 ah1 = *(const bf16x8*)&a2h[RD_][rb_ + 32 + ((quad*8) ^ rsw)]; \
    bf16x8 al1 = *(const bf16x8*)&a2l[RD_][rb_ + 32 + ((quad*8) ^ rsw)]; \
    f32x4 acc[4]; \
    if (wave < 3){ \
      _Pragma("unroll") \
      for (int tt=0; tt<4; ++tt){ \
        f32x4 c0 = __builtin_amdgcn_mfma_f32_16x16x32_bf16(ah0, Bh[tt][0], biasv[tt], 0,0,0); \
        c0 = __builtin_amdgcn_mfma_f32_16x16x32_bf16(al0, Bh[tt][0], c0, 0,0,0); \
        c0 = __builtin_amdgcn_mfma_f32_16x16x32_bf16(ah0, Bl[tt][0], c0, 0,0,0); \
        f32x4 c1 = __builtin_amdgcn_mfma_f32_16x16x32_bf16(ah1, Bh[tt][1], zero4, 0,0,0); \
        c1 = __builtin_amdgcn_mfma_f32_16x16x32_bf16(al1, Bh[tt][1], c1, 0,0,0); \
        c1 = __builtin_amdgcn_mfma_f32_16x16x32_bf16(ah1, Bl[tt][1], c1, 0,0,0); \
        acc[tt] = c0 + c1; \
      } \
    } else { \
      bf16x8 xfH = *(const bf16x8*)&xfh[WR_][l15*XFS + quad*8]; \
      bf16x8 xfL = *(const bf16x8*)&xfl[WR_][l15*XFS + quad*8]; \
      _Pragma("unroll") \
      for (int tt=0; tt<4; ++tt){ \
        f32x4 c0 = __builtin_amdgcn_mfma_f32_16x16x32_bf16(ah0, Bh[tt][0], biasv[tt], 0,0,0); \
        c0 = __builtin_amdgcn_mfma_f32_16x16x32_bf16(al0, Bh[tt][0], c0, 0,0,0); \
        c0 = __builtin_amdgcn_mfma_f32_16x16x32_bf16(ah0, Bl[tt][0], c0, 0,0,0); \
        f32x4 c1 = __builtin_amdgcn_mfma_f32_16x16x32_bf16(ah1, Bh[tt][1], zero4, 0,0,0); \
        c1 = __builtin_amdgcn_mfma_f32_16x16x32_bf16(al1, Bh[tt][1], c1, 0,0,0); \
        c1 = __builtin_amdgcn_mfma_f32_16x16x32_bf16(ah1, Bl[tt][1], c1, 0,0,0); \
        f32x4 c2 = __builtin_amdgcn_mfma_f32_16x16x32_bf16(xfH, Bh[tt][2], zero4, 0,0,0); \
        c2 = __builtin_amdgcn_mfma_f32_16x16x32_bf16(xfL, Bh[tt][2], c2, 0,0,0); \
        c2 = __builtin_amdgcn_mfma_f32_16x16x32_bf16(xfH, Bl[tt][2], c2, 0,0,0); \
        acc[tt] = (c0 + c1) + c2; \
      } \
    } \
    /* act + merged h-write (last LDS write retires before the fence) */ \
    if (wave < 3){ \
      const int wrb = quad*4*72 + ((wave*16 + l15) ^ wsw); \
      _Pragma("unroll") \
      for (int r=0;r<4;r++){ \
        float h; \
        CELL_UPDATE(acc[0][r], acc[1][r], acc[2][r], acc[3][r], cst[r], h); \
        unsigned short hh, hl; split1(h, hh, hl); \
        a2h[WR_][wrb + r*72] = hh; \
        a2l[WR_][wrb + r*72] = hl; \
        if (LAST_){ \
          out[(size_t)B_TOTAL*NCLS + (size_t)(b0+quad*4+r)*H2 + wave*16+l15] = h; \
          h2f[(quad*4+r)*52 + wave*16+l15] = h; \
        } \
      } \
    } else { \
      const int wrb = quad*4*72 + ((48 + l15) ^ wsw);  /* 48,49=h2 | 50..54=h1 */ \
      const bool wv_ = l15 < 7; \
      _Pragma("unroll") \
      for (int r=0;r<4;r++){ \
        float h; \
        CELL_UPDATE(acc[0][r], acc[1][r], acc[2][r], acc[3][r], cst[r], h); \
        if (wv_){ \
          unsigned short hh, hl; split1(h, hh, hl); \
          a2h[WR_][wrb + r*72] = hh; \
          a2l[WR_][wrb + r*72] = hl; \
          if (LAST_ && l15 < 2){ \
            out[(size_t)B_TOTAL*NCLS + (size_t)(b0+quad*4+r)*H2 + 48+l15] = h; \
            h2f[(quad*4+r)*52 + 48+l15] = h; \
          } \
        } \
      } \
    } \
  } while(0)

  // main loop, unrolled x2: compile-time buffer parity and x ping-pong.
  // step T: reads a2[T&1] + xf[(T+1)&1]; writes a2[(T+1)&1]; producer writes
  // xf[T&1] (x(T+2)) and loads x(T+3). Last pair (510,511) peeled so the
  // LAST store-condition is compile-time.
  for (int t2 = 0; t2 < T_STEPS-2; t2 += 2){
    MAIN_BODY(t2,   0, 1, PA, PB, 0);
    LDS_FENCE(); BARRIER();
    MAIN_BODY(t2+1, 1, 0, PB, PA, 0);
    LDS_FENCE(); BARRIER();
  }
  MAIN_BODY(T_STEPS-2, 0, 1, PA, PB, 0);
  LDS_FENCE(); BARRIER();
  MAIN_BODY(T_STEPS-1, 1, 0, PB, PA, 1);

#undef MAIN_BODY

  __syncthreads();
  // fused FC: 16 batches x 20 outputs = 320 results on 256 threads
  for (int i = tid; i < 16*NCLS; i += 256){
    const int b = i / NCLS, o = i % NCLS;
    float s = fc_b[o];
#pragma unroll 10
    for (int k=0;k<H2;k++) s += fc_w[o*H2+k] * h2f[b*52+k];
    out[(size_t)(b0+b)*NCLS + o] = s;
  }
}

extern "C" void kernel_launch(void* const* d_in, const int* in_sizes, int n_in,
                              void* d_out, int out_size, void* d_ws, size_t ws_size,
                              hipStream_t stream) {
  const float* x     = (const float*)d_in[0];
  const float* w_ih1 = (const float*)d_in[1];
  const float* w_hh1 = (const float*)d_in[2];
  const float* b_ih1 = (const float*)d_in[3];
  const float* b_hh1 = (const float*)d_in[4];
  const float* w_ih2 = (const float*)d_in[5];
  const float* w_hh2 = (const float*)d_in[6];
  const float* b_ih2 = (const float*)d_in[7];
  const float* b_hh2 = (const float*)d_in[8];
  const float* fc_w  = (const float*)d_in[9];
  const float* fc_b  = (const float*)d_in[10];
  float* out = (float*)d_out;

  lstm_fused_kernel<<<dim3(B_TOTAL/16), dim3(256), 0, stream>>>(
      x, w_ih1, w_hh1, b_ih1, b_hh1, w_ih2, w_hh2, b_ih2, b_hh2, fc_w, fc_b, out);
}